// Round 1
// baseline (13758.134 us; speedup 1.0000x reference)
//
#include <hip/hip_runtime.h>
#include <math.h>
#include <float.h>

#define N 8192
#define D 64
#define NK 90              // neighbors kept (K+1=91 incl self; self excluded inline)
#define BM 32
#define BN 64
#define NTILE (N / BN)     // 128
#define LCAP 160           // per-row candidate buffer capacity
#define TRIG (LCAP - BN)   // 96: compact when cnt > TRIG so next tile (<=64 appends) fits
#define PITCH_I 36
#define PITCH_J 68

// ---------------- kernel A: squared norms ----------------
__global__ void k_sq(const float* __restrict__ x, float* __restrict__ sq) {
    int r = blockIdx.x * blockDim.x + threadIdx.x;
    if (r < N) {
        const float4* p = (const float4*)(x + r * D);
        float s = 0.f;
#pragma unroll
        for (int q = 0; q < D / 4; ++q) {
            float4 v = p[q];
            s += v.x * v.x + v.y * v.y + v.z * v.z + v.w * v.w;
        }
        sq[r] = s;
    }
}

// serial quickselect: partition v[0..n) so the NK smallest are in v[0..NK); return their max
__device__ float qsel_keep(float* v, unsigned short* id, int n) {
    int lo = 0, hi = n;
    const int k = NK;
    for (int guard = 0; guard < 64 && (hi - lo) > 1; ++guard) {
        float a = v[lo], b = v[lo + ((hi - lo) >> 1)], c = v[hi - 1];
        float p = fmaxf(fminf(a, b), fminf(fmaxf(a, b), c));  // median of 3
        int i = lo, j = hi - 1;
        while (i <= j) {
            while (v[i] < p) ++i;
            while (v[j] > p) --j;
            if (i <= j) {
                float tv = v[i]; v[i] = v[j]; v[j] = tv;
                unsigned short ts = id[i]; id[i] = id[j]; id[j] = ts;
                ++i; --j;
            }
        }
        if (k <= j) hi = j + 1;
        else if (k >= i) lo = i;
        else break;  // boundary lies in equal-to-pivot run: first k are the k smallest
    }
    float mx = v[0];
    for (int e = 1; e < NK; ++e) mx = fmaxf(mx, v[e]);
    return mx;
}

// ---------------- kernel B: fused distance + top-90 selection ----------------
__global__ __launch_bounds__(256) void k_knn(const float* __restrict__ x,
                                             const float* __restrict__ sq,
                                             float* __restrict__ odist,
                                             int* __restrict__ oidx) {
    __shared__ float xi[D][PITCH_I];          // transposed row tile  [dim][row]
    __shared__ float xj[D][PITCH_J];          // transposed col tile  [dim][col]
    __shared__ float sqi[BM];
    __shared__ float sqj[BN];
    __shared__ float bufv[BM][LCAP];
    __shared__ unsigned short bufi[BM][LCAP];
    __shared__ int cnt[BM];
    __shared__ float thr[BM];

    const int tid = threadIdx.x;
    const int row0 = blockIdx.x * BM;

    // stage row tile (transposed): x[row0+r][d] -> xi[d][r]
    for (int e = tid; e < BM * D; e += 256) {
        int r = e >> 6, d = e & 63;
        xi[d][r] = x[(row0 + r) * D + d];
    }
    if (tid < BM) {
        sqi[tid] = sq[row0 + tid];
        cnt[tid] = 0;
        thr[tid] = FLT_MAX;
    }

    const int r0 = (tid >> 5) * 4;  // 0..28
    const int c0 = (tid & 31) * 2;  // 0..62

    for (int t = 0; t < NTILE; ++t) {
        const int col0 = t * BN;
        // stage col tile (transposed), vectorized global loads
        for (int e = tid; e < BN * D / 4; e += 256) {
            int c = e >> 4, d4 = (e & 15) * 4;
            float4 v = *(const float4*)(x + (col0 + c) * D + d4);
            xj[d4 + 0][c] = v.x;
            xj[d4 + 1][c] = v.y;
            xj[d4 + 2][c] = v.z;
            xj[d4 + 3][c] = v.w;
        }
        if (tid < BN) sqj[tid] = sq[col0 + tid];
        __syncthreads();  // (1) tiles staged; prev compaction visible

        float a00 = 0, a01 = 0, a10 = 0, a11 = 0, a20 = 0, a21 = 0, a30 = 0, a31 = 0;
#pragma unroll 4
        for (int k = 0; k < D; ++k) {
            float4 av = *(const float4*)&xi[k][r0];   // broadcast (2 addrs/wave)
            float2 bv = *(const float2*)&xj[k][c0];   // contiguous, conflict-free
            a00 = fmaf(av.x, bv.x, a00); a01 = fmaf(av.x, bv.y, a01);
            a10 = fmaf(av.y, bv.x, a10); a11 = fmaf(av.y, bv.y, a11);
            a20 = fmaf(av.z, bv.x, a20); a21 = fmaf(av.z, bv.y, a21);
            a30 = fmaf(av.w, bv.x, a30); a31 = fmaf(av.w, bv.y, a31);
        }

        const float accs[4][2] = {{a00, a01}, {a10, a11}, {a20, a21}, {a30, a31}};
#pragma unroll
        for (int ar = 0; ar < 4; ++ar) {
            const int rl = r0 + ar;
            const float thv = thr[rl];
            const float s_i = sqi[rl];
            const int gi = row0 + rl;
#pragma unroll
            for (int bc = 0; bc < 2; ++bc) {
                const int gj = col0 + c0 + bc;
                const float d2 = s_i + sqj[c0 + bc] - 2.0f * accs[ar][bc];
                if (d2 < thv && gj != gi) {
                    const int pos = atomicAdd(&cnt[rl], 1);
                    bufv[rl][pos] = d2;
                    bufi[rl][pos] = (unsigned short)gj;
                }
            }
        }
        __syncthreads();  // (2) appends done

        // owner-lane compaction (wave 0, lanes 0..31)
        if (tid < BM) {
            int n = cnt[tid];
            if (n > TRIG) {
                thr[tid] = qsel_keep(bufv[tid], bufi[tid], n);
                cnt[tid] = NK;
            }
        }
        // next iter's barrier (1) orders compaction before the next append phase;
        // xj restage only touches memory disjoint from buf/cnt/thr.
    }

    if (tid < BM) {
        int n = cnt[tid];
        if (n > NK) (void)qsel_keep(bufv[tid], bufi[tid], n);
    }
    __syncthreads();

    for (int e = tid; e < BM * NK; e += 256) {
        int r = e / NK, k = e - r * NK;
        odist[(row0 + r) * NK + k] = sqrtf(fmaxf(bufv[r][k], 0.f));
        oidx[(row0 + r) * NK + k] = (int)bufi[r][k];
    }
}

// ---------------- kernel C: beta bisection + inverse Simpson ----------------
__global__ __launch_bounds__(256) void k_lisi(const float* __restrict__ dist,
                                              const int* __restrict__ idx,
                                              const int* __restrict__ batch,
                                              float* __restrict__ out) {
    const int wave = threadIdx.x >> 6;
    const int lane = threadIdx.x & 63;
    const int row = blockIdx.x * 4 + wave;

    const float logU = 3.4011974f;  // ln(30)

    const float d0 = dist[row * NK + lane];
    const int i0 = idx[row * NK + lane];
    const bool v1 = lane < (NK - 64);  // 26 extra lanes
    const float d1 = v1 ? dist[row * NK + 64 + lane] : 0.f;
    const int i1 = v1 ? idx[row * NK + 64 + lane] : 0;
    const int l0 = batch[i0];
    const int l1 = v1 ? batch[i1] : -1;

    float beta = 1.f, bmin = -INFINITY, bmax = INFINITY;
    float P0, P1, S, H;

    auto hbeta = [&](float b) {
        P0 = __expf(-d0 * b);
        P1 = v1 ? __expf(-d1 * b) : 0.f;
        float s = P0 + P1;
        float w = d0 * P0 + (v1 ? d1 * P1 : 0.f);
        for (int o = 32; o > 0; o >>= 1) {
            s += __shfl_xor(s, o, 64);
            w += __shfl_xor(w, o, 64);
        }
        S = s;
        H = (S > 0.f) ? (__logf(S) + b * w / S) : 0.f;
    };

    hbeta(beta);
    float Hdiff = H - logU;
    for (int it = 0; it < 50; ++it) {
        if (fabsf(Hdiff) < 1e-5f) break;
        if (Hdiff > 0.f) {
            bmin = beta;
            beta = isinf(bmax) ? beta * 2.f : 0.5f * (beta + bmax);
        } else {
            bmax = beta;
            beta = isinf(bmin) ? beta * 0.5f : 0.5f * (beta + bmin);
        }
        hbeta(beta);
        Hdiff = H - logU;
    }

    const float Pn0 = (S > 0.f) ? P0 / S : 0.f;
    const float Pn1 = (S > 0.f && v1) ? P1 / S : 0.f;

    float simpson = 0.f;
#pragma unroll
    for (int c = 0; c < 8; ++c) {
        float v = (l0 == c ? Pn0 : 0.f) + (l1 == c ? Pn1 : 0.f);
        for (int o = 32; o > 0; o >>= 1) v += __shfl_xor(v, o, 64);
        simpson += v * v;
    }
    if (H == 0.f) simpson -= 1.f;
    if (lane == 0) out[row] = 1.f / simpson;
}

extern "C" void kernel_launch(void* const* d_in, const int* in_sizes, int n_in,
                              void* d_out, int out_size, void* d_ws, size_t ws_size,
                              hipStream_t stream) {
    const float* x = (const float*)d_in[0];
    const int* batch = (const int*)d_in[1];
    float* out = (float*)d_out;

    float* sq = (float*)d_ws;                // [N]
    float* dist = sq + N;                    // [N*NK]
    int* idx = (int*)(dist + (size_t)N * NK);  // [N*NK]

    k_sq<<<N / 256, 256, 0, stream>>>(x, sq);
    k_knn<<<N / BM, 256, 0, stream>>>(x, sq, dist, idx);
    k_lisi<<<N / 4, 256, 0, stream>>>(dist, idx, batch, out);
}

// Round 2
// 587.113 us; speedup vs baseline: 23.4335x; 23.4335x over previous
//
#include <hip/hip_runtime.h>
#include <math.h>
#include <float.h>

#define N 8192
#define D 64
#define NK 90               // neighbors kept (K+1=91 incl self; self excluded at append)
#define BM 32
#define BN 128
#define NT (N / BN)         // 64 col tiles
#define LCAP 448            // per-row candidate capacity (= TRIG + BN)
#define TRIG (LCAP - BN)    // 320: compact when cnt > TRIG
#define WKEEP 160           // loose keep bound for mid-loop compaction early-stop
#define QS 7                // ceil(LCAP/64) register slots per lane
#define PI_I 36             // xi pitch (32+4)

// ---------------- kernel A: squared norms ----------------
__global__ void k_sq(const float* __restrict__ x, float* __restrict__ sq) {
    int r = blockIdx.x * blockDim.x + threadIdx.x;
    if (r < N) {
        const float4* p = (const float4*)(x + r * D);
        float s = 0.f;
#pragma unroll
        for (int q = 0; q < D / 4; ++q) {
            float4 v = p[q];
            s += v.x * v.x + v.y * v.y + v.z * v.z + v.w * v.w;
        }
        sq[r] = s;
    }
}

// ---------------- wave-parallel top-90 select (bit bisection on f32-as-u32) ----
// 64 lanes cooperatively select over bufv[r][0..n); keeps the <=WKEEP smallest
// (loose mode) or exactly the NK smallest (exact mode), compacted to the front.
__device__ void wave_select(float (*bufv)[LCAP], unsigned short (*bufi)[LCAP],
                            int* cnt, float* thr, int* scnt, int* scnt2,
                            int r, int n, bool exact) {
    const int lane = threadIdx.x & 63;
    float fv[QS]; unsigned short fi[QS]; unsigned uv[QS]; bool val[QS];
#pragma unroll
    for (int q = 0; q < QS; ++q) {
        int e = lane + 64 * q;
        val[q] = e < n;
        fv[q] = val[q] ? bufv[r][e] : 0.f;
        fi[q] = val[q] ? bufi[r][e] : (unsigned short)0;
        uv[q] = __float_as_uint(fv[q]);
    }
    // invariant: count(u <= Tlo) < NK <= count(u <= Thi)
    unsigned Tlo = 0u, Thi = 0xFFFFFFFFu;
    int chi = n;
    while (Thi - Tlo > 1u) {
        unsigned Tm = Tlo + ((Thi - Tlo) >> 1);
        int c = 0;
#pragma unroll
        for (int q = 0; q < QS; ++q)
            c += __popcll(__ballot(val[q] && uv[q] <= Tm));
        if (c >= NK) { Thi = Tm; chi = c; if (!exact && c <= WKEEP) break; }
        else Tlo = Tm;
    }
    if (lane == 0) { scnt[r] = 0; scnt2[r] = 0; }
    if (!exact) {
        // keep everything <= Thi (90 <= chi <= WKEEP); superset of true top-90
#pragma unroll
        for (int q = 0; q < QS; ++q)
            if (val[q] && uv[q] <= Thi) {
                int pos = atomicAdd(&scnt[r], 1);
                bufv[r][pos] = fv[q]; bufi[r][pos] = fi[q];
            }
        if (lane == 0) { cnt[r] = chi; thr[r] = __uint_as_float(Thi); }
    } else {
        // Thi == exact 90th smallest value; keep all < Thi plus (NK-c1) ties
        int c1 = 0;
#pragma unroll
        for (int q = 0; q < QS; ++q)
            c1 += __popcll(__ballot(val[q] && uv[q] < Thi));
#pragma unroll
        for (int q = 0; q < QS; ++q)
            if (val[q]) {
                if (uv[q] < Thi) {
                    int pos = atomicAdd(&scnt[r], 1);
                    bufv[r][pos] = fv[q]; bufi[r][pos] = fi[q];
                } else if (uv[q] == Thi) {
                    int t2 = atomicAdd(&scnt2[r], 1);
                    if (t2 < NK - c1) { bufv[r][c1 + t2] = fv[q]; bufi[r][c1 + t2] = fi[q]; }
                }
            }
        if (lane == 0) cnt[r] = NK;
    }
}

// ---------------- kernel B: fused distance + top-90 ----------------
__global__ __launch_bounds__(256) void k_knn(const float* __restrict__ x,
                                             const float* __restrict__ sq,
                                             float* __restrict__ odist,
                                             int* __restrict__ oidx) {
    __shared__ float xi[D][PI_I];        // transposed row tile
    __shared__ float xj[D * BN];         // transposed col tile, XOR-swizzled
    __shared__ float sqi[BM];
    __shared__ float sqj[BN];
    __shared__ float bufv[BM][LCAP];
    __shared__ unsigned short bufi[BM][LCAP];
    __shared__ int cnt[BM];
    __shared__ float thr[BM];
    __shared__ int scnt[BM];
    __shared__ int scnt2[BM];

    const int tid = threadIdx.x;
    const int row0 = blockIdx.x * BM;

    // stage row tile transposed (one-time)
    for (int e = tid; e < BM * D; e += 256) {
        int r = e >> 6, d = e & 63;
        xi[d][r] = x[(row0 + r) * D + d];
    }
    if (tid < BM) { sqi[tid] = sq[row0 + tid]; cnt[tid] = 0; thr[tid] = FLT_MAX; }

    float4 pf[8];
    float sqpf = 0.f;
    // load tile 0 into regs
#pragma unroll
    for (int q = 0; q < 8; ++q) {
        int e = tid + q * 256;
        int c = e >> 4, d4 = (e & 15) * 4;
        pf[q] = *(const float4*)(x + (size_t)c * D + d4);
    }
    if (tid < BN) sqpf = sq[tid];
    // store tile 0 (swizzled transpose); xj untouched by anyone yet
#pragma unroll
    for (int q = 0; q < 8; ++q) {
        int e = tid + q * 256;
        int c = e >> 4, d4 = (e & 15) * 4;
        const float vv[4] = {pf[q].x, pf[q].y, pf[q].z, pf[q].w};
#pragma unroll
        for (int jj = 0; jj < 4; ++jj) {
            int d = d4 + jj;
            xj[d * BN + (c ^ (((d >> 2) & 7) << 2))] = vv[jj];
        }
    }
    if (tid < BN) sqj[tid] = sqpf;
    __syncthreads();

    const int r0 = (tid >> 5) * 4;   // 0..28
    const int c0 = (tid & 31) * 4;   // 0..124
    const int wv = tid >> 6;         // wave id 0..3

    for (int t = 0; t < NT; ++t) {
        const int col0 = t * BN;
        // T14: issue next tile's global loads into regs (hidden under compute)
        if (t + 1 < NT) {
            const int nc0 = (t + 1) * BN;
#pragma unroll
            for (int q = 0; q < 8; ++q) {
                int e = tid + q * 256;
                int c = e >> 4, d4 = (e & 15) * 4;
                pf[q] = *(const float4*)(x + (size_t)(nc0 + c) * D + d4);
            }
            if (tid < BN) sqpf = sq[nc0 + tid];
        }

        // 4x4 micro-tile GEMM over LDS
        float acc[4][4];
#pragma unroll
        for (int i = 0; i < 4; ++i)
#pragma unroll
            for (int j = 0; j < 4; ++j) acc[i][j] = 0.f;
#pragma unroll 4
        for (int k = 0; k < D; ++k) {
            float4 av = *(const float4*)&xi[k][r0];
            float4 bv = *(const float4*)&xj[k * BN + (c0 ^ (((k >> 2) & 7) << 2))];
            const float aa[4] = {av.x, av.y, av.z, av.w};
            const float bb[4] = {bv.x, bv.y, bv.z, bv.w};
#pragma unroll
            for (int i = 0; i < 4; ++i)
#pragma unroll
                for (int j = 0; j < 4; ++j)
                    acc[i][j] = fmaf(aa[i], bb[j], acc[i][j]);
        }

        // threshold test + append
        float4 sq4 = *(const float4*)&sqj[c0];
        const float sb[4] = {sq4.x, sq4.y, sq4.z, sq4.w};
#pragma unroll
        for (int i = 0; i < 4; ++i) {
            const int rl = r0 + i;
            const float thv = thr[rl];
            const float s_i = sqi[rl];
            const int gi = row0 + rl;
#pragma unroll
            for (int j = 0; j < 4; ++j) {
                const int gj = col0 + c0 + j;
                const float d2 = s_i + sb[j] - 2.0f * acc[i][j];
                if (d2 < thv && gj != gi) {
                    int pos = atomicAdd(&cnt[rl], 1);
                    bufv[rl][pos] = d2;
                    bufi[rl][pos] = (unsigned short)gj;
                }
            }
        }
        __syncthreads();  // (A) xj reads + appends done

        // write prefetched tile into LDS (disjoint from compaction's buffers)
        if (t + 1 < NT) {
#pragma unroll
            for (int q = 0; q < 8; ++q) {
                int e = tid + q * 256;
                int c = e >> 4, d4 = (e & 15) * 4;
                const float vv[4] = {pf[q].x, pf[q].y, pf[q].z, pf[q].w};
#pragma unroll
                for (int jj = 0; jj < 4; ++jj) {
                    int d = d4 + jj;
                    xj[d * BN + (c ^ (((d >> 2) & 7) << 2))] = vv[jj];
                }
            }
            if (tid < BN) sqj[tid] = sqpf;
        }

        // wave-parallel compaction: wave wv owns rows wv*8 .. wv*8+7
#pragma unroll 1
        for (int rr = 0; rr < 8; ++rr) {
            int r = wv * 8 + rr;
            int n = cnt[r];
            if (n > TRIG) wave_select(bufv, bufi, cnt, thr, scnt, scnt2, r, n, false);
        }
        __syncthreads();  // (B) next tile staged; cnt/thr updated
    }

    // final exact top-90 per row
#pragma unroll 1
    for (int rr = 0; rr < 8; ++rr) {
        int r = wv * 8 + rr;
        int n = cnt[r];
        if (n > NK) wave_select(bufv, bufi, cnt, thr, scnt, scnt2, r, n, true);
    }
    __syncthreads();

    for (int e = tid; e < BM * NK; e += 256) {
        int r = e / NK, k = e - r * NK;
        odist[(row0 + r) * NK + k] = sqrtf(fmaxf(bufv[r][k], 0.f));
        oidx[(row0 + r) * NK + k] = (int)bufi[r][k];
    }
}

// ---------------- kernel C: beta bisection + inverse Simpson ----------------
__global__ __launch_bounds__(256) void k_lisi(const float* __restrict__ dist,
                                              const int* __restrict__ idx,
                                              const int* __restrict__ batch,
                                              float* __restrict__ out) {
    const int wave = threadIdx.x >> 6;
    const int lane = threadIdx.x & 63;
    const int row = blockIdx.x * 4 + wave;

    const float logU = 3.4011974f;  // ln(30)

    const float d0 = dist[row * NK + lane];
    const int i0 = idx[row * NK + lane];
    const bool v1 = lane < (NK - 64);  // 26 extra lanes
    const float d1 = v1 ? dist[row * NK + 64 + lane] : 0.f;
    const int i1 = v1 ? idx[row * NK + 64 + lane] : 0;
    const int l0 = batch[i0];
    const int l1 = v1 ? batch[i1] : -1;

    float beta = 1.f, bmin = -INFINITY, bmax = INFINITY;
    float P0, P1, S, H;

    auto hbeta = [&](float b) {
        P0 = __expf(-d0 * b);
        P1 = v1 ? __expf(-d1 * b) : 0.f;
        float s = P0 + P1;
        float w = d0 * P0 + (v1 ? d1 * P1 : 0.f);
        for (int o = 32; o > 0; o >>= 1) {
            s += __shfl_xor(s, o, 64);
            w += __shfl_xor(w, o, 64);
        }
        S = s;
        H = (S > 0.f) ? (__logf(S) + b * w / S) : 0.f;
    };

    hbeta(beta);
    float Hdiff = H - logU;
    for (int it = 0; it < 50; ++it) {
        if (fabsf(Hdiff) < 1e-5f) break;
        if (Hdiff > 0.f) {
            bmin = beta;
            beta = isinf(bmax) ? beta * 2.f : 0.5f * (beta + bmax);
        } else {
            bmax = beta;
            beta = isinf(bmin) ? beta * 0.5f : 0.5f * (beta + bmin);
        }
        hbeta(beta);
        Hdiff = H - logU;
    }

    const float Pn0 = (S > 0.f) ? P0 / S : 0.f;
    const float Pn1 = (S > 0.f && v1) ? P1 / S : 0.f;

    float simpson = 0.f;
#pragma unroll
    for (int c = 0; c < 8; ++c) {
        float v = (l0 == c ? Pn0 : 0.f) + (l1 == c ? Pn1 : 0.f);
        for (int o = 32; o > 0; o >>= 1) v += __shfl_xor(v, o, 64);
        simpson += v * v;
    }
    if (H == 0.f) simpson -= 1.f;
    if (lane == 0) out[row] = 1.f / simpson;
}

extern "C" void kernel_launch(void* const* d_in, const int* in_sizes, int n_in,
                              void* d_out, int out_size, void* d_ws, size_t ws_size,
                              hipStream_t stream) {
    const float* x = (const float*)d_in[0];
    const int* batch = (const int*)d_in[1];
    float* out = (float*)d_out;

    float* sq = (float*)d_ws;                  // [N]
    float* dist = sq + N;                      // [N*NK]
    int* idx = (int*)(dist + (size_t)N * NK);  // [N*NK]

    k_sq<<<N / 256, 256, 0, stream>>>(x, sq);
    k_knn<<<N / BM, 256, 0, stream>>>(x, sq, dist, idx);
    k_lisi<<<N / 4, 256, 0, stream>>>(dist, idx, batch, out);
}